// Round 1
// baseline (4437.605 us; speedup 1.0000x reference)
//
#include <hip/hip_runtime.h>
#include <hip/hip_bf16.h>

// Layout of workspace (floats): [h1: N*32][h2: N*32][gbuf: 64*32][A: N*32][B: N*32]
// h1/h2/gbuf store non-negative float bit patterns (atomicMax on uint).

__global__ __launch_bounds__(256) void pre1_kernel(
    const float* __restrict__ pos, const float* __restrict__ w1a,
    const float* __restrict__ b1a, float* __restrict__ A, float* __restrict__ B, int N)
{
    int t = blockIdx.x * 256 + threadIdx.x;
    if (t >= N * 32) return;
    int n = t >> 5, c = t & 31;
    float px = pos[2 * n], py = pos[2 * n + 1];
    float w0 = w1a[c], w1 = w1a[32 + c], w2 = w1a[64 + c], w3 = w1a[96 + c];
    A[t] = fmaf(px, w0 + w2, fmaf(py, w1 + w3, b1a[c]));
    B[t] = -(px * w2 + py * w3);
}

__global__ __launch_bounds__(256) void pre2_kernel(
    const float* __restrict__ pos, const float* __restrict__ h1,
    const float* __restrict__ w2a, const float* __restrict__ b2a,
    float* __restrict__ C, float* __restrict__ D, int N)
{
    int t = blockIdx.x * 256 + threadIdx.x;
    if (t >= N * 32) return;
    int n = t >> 5, c = t & 31;
    float px = pos[2 * n], py = pos[2 * n + 1];
    float wx = w2a[32 * 32 + c], wy = w2a[33 * 32 + c];
    float s = fmaf(px, wx, fmaf(py, wy, b2a[c]));
    const float* hrow = h1 + n * 32;
#pragma unroll
    for (int k = 0; k < 32; ++k) s = fmaf(hrow[k], w2a[k * 32 + c], s);
    C[t] = s;
    D[t] = -(px * wx + py * wy);
}

__global__ __launch_bounds__(256) void edge_mlp_kernel(
    const int* __restrict__ ei,            // [2, E]
    const float* __restrict__ Anode,       // [N,32] (src side, bias folded)
    const float* __restrict__ Bnode,       // [N,32] (dst side)
    const float* __restrict__ w,           // [32,32] row-major
    const float* __restrict__ bias,        // [32]
    unsigned int* __restrict__ out,        // [N,32] uint-bits, 0-initialized
    int E)
{
    int e = blockIdx.x * 256 + threadIdx.x;
    if (e >= E) return;
    int src = ei[e];
    int dst = ei[E + e];
    const float4* ap = (const float4*)(Anode + src * 32);
    const float4* bp = (const float4*)(Bnode + dst * 32);
    float h[32];
#pragma unroll
    for (int q = 0; q < 8; ++q) {
        float4 a = ap[q];
        float4 b = bp[q];
        h[4 * q + 0] = fmaxf(a.x + b.x, 0.0f);
        h[4 * q + 1] = fmaxf(a.y + b.y, 0.0f);
        h[4 * q + 2] = fmaxf(a.z + b.z, 0.0f);
        h[4 * q + 3] = fmaxf(a.w + b.w, 0.0f);
    }
    float m[32];
#pragma unroll
    for (int c = 0; c < 32; ++c) m[c] = bias[c];
#pragma unroll
    for (int k = 0; k < 32; ++k) {
        float hk = h[k];
#pragma unroll
        for (int c = 0; c < 32; ++c) m[c] = fmaf(hk, w[k * 32 + c], m[c]);
    }
    unsigned int base = (unsigned int)dst * 32u;
#pragma unroll
    for (int c = 0; c < 32; ++c) {
        if (m[c] > 0.0f) atomicMax(out + base + c, __float_as_uint(m[c]));
    }
}

__global__ __launch_bounds__(256) void pool_kernel(
    const float* __restrict__ h2, const int* __restrict__ batch,
    unsigned int* __restrict__ gbuf, int N)
{
    int t = blockIdx.x * 256 + threadIdx.x;
    if (t >= N * 32) return;
    int n = t >> 5, c = t & 31;
    float v = h2[t];
    if (v > 0.0f) atomicMax(gbuf + batch[n] * 32 + c, __float_as_uint(v));
}

__global__ __launch_bounds__(192) void out_kernel(
    const unsigned int* __restrict__ gbuf, const float* __restrict__ wc,
    const float* __restrict__ bc, float* __restrict__ out, int G)
{
    int t = threadIdx.x;
    if (t >= G * 3) return;
    int g = t / 3, j = t % 3;
    float s = bc[j];
#pragma unroll
    for (int c = 0; c < 32; ++c)
        s = fmaf(__uint_as_float(gbuf[g * 32 + c]), wc[c * 3 + j], s);
    out[t] = s;
}

extern "C" void kernel_launch(void* const* d_in, const int* in_sizes, int n_in,
                              void* d_out, int out_size, void* d_ws, size_t ws_size,
                              hipStream_t stream) {
    const float* pos = (const float*)d_in[0];
    const float* w1a = (const float*)d_in[1];
    const float* b1a = (const float*)d_in[2];
    const float* w1b = (const float*)d_in[3];
    const float* b1b = (const float*)d_in[4];
    const float* w2a = (const float*)d_in[5];
    const float* b2a = (const float*)d_in[6];
    const float* w2b = (const float*)d_in[7];
    const float* b2b = (const float*)d_in[8];
    const float* wc  = (const float*)d_in[9];
    const float* bc  = (const float*)d_in[10];
    const int* ei    = (const int*)d_in[11];
    const int* batch = (const int*)d_in[12];

    const int N = in_sizes[12];
    const int E = in_sizes[11] / 2;
    const int G = out_size / 3;
    const size_t NC = (size_t)N * 32;

    float* h1   = (float*)d_ws;
    float* h2   = h1 + NC;
    unsigned int* gbuf = (unsigned int*)(h2 + NC);
    float* A    = (float*)(gbuf + (size_t)G * 32);
    float* B    = A + NC;

    // zero h1, h2, gbuf in one shot (contiguous)
    hipMemsetAsync(d_ws, 0, (2 * NC + (size_t)G * 32) * sizeof(float), stream);

    int nThreads = (int)NC;
    int nBlocks = (nThreads + 255) / 256;
    int eBlocks = (E + 255) / 256;

    pre1_kernel<<<nBlocks, 256, 0, stream>>>(pos, w1a, b1a, A, B, N);
    edge_mlp_kernel<<<eBlocks, 256, 0, stream>>>(ei, A, B, w1b, b1b,
                                                 (unsigned int*)h1, E);
    pre2_kernel<<<nBlocks, 256, 0, stream>>>(pos, h1, w2a, b2a, A, B, N);
    edge_mlp_kernel<<<eBlocks, 256, 0, stream>>>(ei, A, B, w2b, b2b,
                                                 (unsigned int*)h2, E);
    pool_kernel<<<nBlocks, 256, 0, stream>>>(h2, batch, gbuf, N);
    out_kernel<<<1, 192, 0, stream>>>(gbuf, wc, bc, (float*)d_out, G);
}